// Round 4
// baseline (735.342 us; speedup 1.0000x reference)
//
#include <hip/hip_runtime.h>
#include <stdint.h>

#define B_ 2
#define T_ 1024
#define C_ 2048
#define H_ 16
#define D_ 128
#define P_ 1024
#define L_ 2048   // P + T
#define M_ 2048   // B*T

typedef unsigned short u16;
typedef __attribute__((ext_vector_type(8))) short short8;   // MFMA A/B frag (8 bf16)
typedef __attribute__((ext_vector_type(4))) float f32x4;    // MFMA C/D frag
typedef __attribute__((ext_vector_type(8))) u16 u16x8;      // 16B LDS vector
typedef __attribute__((ext_vector_type(4))) u16 u16x4;      // 8B LDS vector

__device__ __forceinline__ u16 f2bf(float x) {
    union { float f; uint32_t u; } c; c.f = x;
    uint32_t u = c.u;
    return (u16)((u + 0x7fffu + ((u >> 16) & 1u)) >> 16);   // RNE
}

// ---------------------------------------------------------------------------
__global__ __launch_bounds__(256) void zero_ws_kernel(u16x8* __restrict__ p) {
    p[blockIdx.x * 256 + threadIdx.x] = u16x8{0,0,0,0,0,0,0,0};
}

// ---------------------------------------------------------------------------
// Copy past_k/past_v [B,H,P,D] f32 into k/v cache [B,H,L,D] f32 at l < P.
__global__ __launch_bounds__(256) void copy_past_kernel(
        const float4* __restrict__ pk, const float4* __restrict__ pv,
        float4* __restrict__ kdst, float4* __restrict__ vdst) {
    int i = blockIdx.x * 256 + threadIdx.x;   // float4 idx; total B*H*P*D/4 = 1048576
    int bh = i >> 15;                          // / (P*D/4 = 32768)
    int rest = i & 32767;
    size_t dst = (size_t)bh * (L_ * D_ / 4) + rest;
    kdst[dst] = pk[i];
    vdst[dst] = pv[i];
}

// ---------------------------------------------------------------------------
// NT GEMM: C[m,n] = sum_k A[m,k]*B[n,k]. B: f32 [N,K] (weights, x@W.T).
// ADT 0: A f32 [M,K].  ADT 1: A bf16 [M,K].
// MODE 0: store bf16 to outb[m*N+n] (Q staging).
// MODE 1: scatter f32 into KV cache [B,H,L,D] at l = P + t.
// MODE 2: store f32 out[m*N+n] + bias[n].
// 64x64 tile, 256 threads (4 waves), K-tile 32, bf16 MFMA accumulation in f32.
template <int MODE, int ADT>
__global__ __launch_bounds__(256) void gemm_nt(
        const void* __restrict__ Av, const float* __restrict__ Bm,
        void* __restrict__ outv, const float* __restrict__ bias) {
    __shared__ u16 As[64][40];   // 80B rows (16B-aligned)
    __shared__ u16 Bs[64][40];
    const int tid  = threadIdx.x;
    const int wave = tid >> 6;
    const int lane = tid & 63;
    const int m0 = blockIdx.y * 64;
    const int n0 = blockIdx.x * 64;

    f32x4 acc[4];
#pragma unroll
    for (int j = 0; j < 4; ++j) acc[j] = f32x4{0.f, 0.f, 0.f, 0.f};

    const int lr = tid >> 2;          // staging row 0..63
    const int lc = (tid & 3) * 8;     // staging col segment (8 elems)

    const float* Af  = (const float*)Av;
    const u16*   Ab  = (const u16*)Av;
    const float* Bp  = Bm + (size_t)(n0 + lr) * C_ + lc;

    const int frow = lane & 15;       // frag row
    const int fko  = (lane >> 4) * 8; // frag k offset

    for (int kt = 0; kt < C_; kt += 32) {
        u16x8 av;
        if (ADT == 0) {
            const float* ap = Af + (size_t)(m0 + lr) * C_ + lc + kt;
            float4 a0 = *(const float4*)(ap);
            float4 a1 = *(const float4*)(ap + 4);
            av = u16x8{f2bf(a0.x), f2bf(a0.y), f2bf(a0.z), f2bf(a0.w),
                       f2bf(a1.x), f2bf(a1.y), f2bf(a1.z), f2bf(a1.w)};
        } else {
            av = *(const u16x8*)(Ab + (size_t)(m0 + lr) * C_ + lc + kt);
        }
        float4 b0 = *(const float4*)(Bp + kt);
        float4 b1 = *(const float4*)(Bp + kt + 4);
        u16x8 bv = u16x8{f2bf(b0.x), f2bf(b0.y), f2bf(b0.z), f2bf(b0.w),
                         f2bf(b1.x), f2bf(b1.y), f2bf(b1.z), f2bf(b1.w)};
        __syncthreads();
        *(u16x8*)&As[lr][lc] = av;
        *(u16x8*)&Bs[lr][lc] = bv;
        __syncthreads();
        short8 a = *(const short8*)&As[wave * 16 + frow][fko];
#pragma unroll
        for (int j = 0; j < 4; ++j) {
            short8 b = *(const short8*)&Bs[j * 16 + frow][fko];
            acc[j] = __builtin_amdgcn_mfma_f32_16x16x32_bf16(a, b, acc[j], 0, 0, 0);
        }
    }

    // C/D layout: col = lane&15, row = (lane>>4)*4 + reg  [verified m89/m91]
    const int ccol = lane & 15;
    const int crb  = (lane >> 4) * 4;
#pragma unroll
    for (int j = 0; j < 4; ++j) {
        int gc = n0 + j * 16 + ccol;
        float badd = (MODE == 2) ? bias[gc] : 0.f;
#pragma unroll
        for (int r = 0; r < 4; ++r) {
            int gr = m0 + wave * 16 + crb + r;
            float v = acc[j][r] + badd;
            if (MODE == 0) {
                ((u16*)outv)[(size_t)gr * C_ + gc] = f2bf(v);
            } else if (MODE == 1) {
                int b = gr >> 10, t = gr & 1023;   // gr = b*T + t
                int h = gc >> 7,  d = gc & 127;    // gc = h*D + d
                ((float*)outv)[(((size_t)(b * H_ + h)) * L_ + P_ + t) * D_ + d] = v;
            } else {
                ((float*)outv)[(size_t)gr * C_ + gc] = v;
            }
        }
    }
}

// ---------------------------------------------------------------------------
// MFMA flash attention. One block = (b, h, 64 query rows). K/V chunks of 64.
// Q: bf16 [B,T,C] staging. Kc/Vc: f32 cache [B,H,L,D]. O: bf16 [B,T,C].
#define NEG_BIG -30000.f
__global__ __launch_bounds__(256) void attn_kernel(
        const u16* __restrict__ Q, const float* __restrict__ Kc,
        const float* __restrict__ Vc, u16* __restrict__ O) {
    __shared__ u16 Qs[64][128];
    __shared__ u16 Ks[64][128];
    __shared__ u16 VsT[128][72];  // transposed V chunk: VsT[d][key]
    __shared__ u16 Ps[64][72];    // P tile

    const int tid  = threadIdx.x;
    const int wave = tid >> 6;
    const int lane = tid & 63;
    const int qt = blockIdx.x & 15;          // T/64 = 16 q-tiles
    const int h  = (blockIdx.x >> 4) & 15;
    const int b  = blockIdx.x >> 8;
    const int t0 = qt * 64;

    const float* Kb = Kc + ((size_t)(b * H_ + h)) * L_ * D_;
    const float* Vb = Vc + ((size_t)(b * H_ + h)) * L_ * D_;

    // Stage Q tile (64 rows x 128 dims, bf16 source)
    {
        int r  = tid >> 2;
        int d0 = (tid & 3) * 32;
        const u16* src = Q + ((size_t)(b * T_ + t0 + r)) * C_ + h * D_ + d0;
#pragma unroll
        for (int u = 0; u < 4; ++u)
            *(u16x8*)&Qs[r][d0 + u * 8] = *(const u16x8*)(src + u * 8);
    }

    const int frow = lane & 15;
    const int quad = lane >> 4;
    const int fko  = quad * 8;

    f32x4 o_acc[8];
#pragma unroll
    for (int n = 0; n < 8; ++n) o_acc[n] = f32x4{0.f, 0.f, 0.f, 0.f};
    float m_i[4] = {NEG_BIG, NEG_BIG, NEG_BIG, NEG_BIG};
    float l_i[4] = {0.f, 0.f, 0.f, 0.f};
    const float scale = 0.08838834764831845f;   // 1/sqrt(128)

    const int nch = (P_ + t0 + 64) >> 6;

    for (int ch = 0; ch < nch; ++ch) {
        const int j0 = ch * 64;
        __syncthreads();   // prior iter's LDS consumers done (covers Q staging too)
        {   // stage K chunk (row-major) and V chunk (transposed), f32 -> bf16
            const float* kg = Kb + (size_t)j0 * D_;
            const float* vg = Vb + (size_t)j0 * D_;
#pragma unroll
            for (int s = 0; s < 8; ++s) {
                int e = s * 1024 + tid * 4;       // element idx within 64x128
                int kr = e >> 7, kc = e & 127;
                float4 k4 = *(const float4*)(kg + e);
                *(u16x4*)&Ks[kr][kc] = u16x4{f2bf(k4.x), f2bf(k4.y),
                                             f2bf(k4.z), f2bf(k4.w)};
                float4 v4 = *(const float4*)(vg + e);
                VsT[kc + 0][kr] = f2bf(v4.x);
                VsT[kc + 1][kr] = f2bf(v4.y);
                VsT[kc + 2][kr] = f2bf(v4.z);
                VsT[kc + 3][kr] = f2bf(v4.w);
            }
        }
        __syncthreads();

        // S = Q_tile(wave's 16 rows) @ K_chunk^T  -> 4 col-tiles of 16 keys
        f32x4 st[4];
#pragma unroll
        for (int j = 0; j < 4; ++j) st[j] = f32x4{0.f, 0.f, 0.f, 0.f};
#pragma unroll
        for (int kt = 0; kt < 4; ++kt) {
            short8 a = *(const short8*)&Qs[wave * 16 + frow][kt * 32 + fko];
#pragma unroll
            for (int j = 0; j < 4; ++j) {
                short8 bf = *(const short8*)&Ks[j * 16 + frow][kt * 32 + fko];
                st[j] = __builtin_amdgcn_mfma_f32_16x16x32_bf16(a, bf, st[j], 0, 0, 0);
            }
        }

        // Online softmax. Lane holds rows quad*4+r, col frow (+16j).
#pragma unroll
        for (int r = 0; r < 4; ++r) {
            const int t   = t0 + wave * 16 + quad * 4 + r;
            const int lim = P_ + t;      // attend keys j <= lim
            float sv[4];
            float mx = NEG_BIG;
#pragma unroll
            for (int j = 0; j < 4; ++j) {
                int jg = j0 + j * 16 + frow;
                float s = st[j][r] * scale;
                s = (jg <= lim) ? s : NEG_BIG;
                sv[j] = s;
                mx = fmaxf(mx, s);
            }
#pragma unroll
            for (int sft = 1; sft <= 8; sft <<= 1)
                mx = fmaxf(mx, __shfl_xor(mx, sft, 64));
            float m_new = fmaxf(m_i[r], mx);
            float alpha = __expf(fminf(m_i[r] - m_new, 0.f));
            float rs = 0.f;
#pragma unroll
            for (int j = 0; j < 4; ++j) {
                float p = __expf(fminf(sv[j] - m_new, 0.f));
                p = (sv[j] <= NEG_BIG) ? 0.f : p;   // masked -> exactly 0
                sv[j] = p;
                rs += p;
            }
#pragma unroll
            for (int sft = 1; sft <= 8; sft <<= 1)
                rs += __shfl_xor(rs, sft, 64);
            l_i[r] = l_i[r] * alpha + rs;
            m_i[r] = m_new;
#pragma unroll
            for (int n = 0; n < 8; ++n) o_acc[n][r] *= alpha;
#pragma unroll
            for (int j = 0; j < 4; ++j)
                Ps[wave * 16 + quad * 4 + r][j * 16 + frow] = f2bf(sv[j]);
        }
        __syncthreads();   // Ps stores visible before vector reads

        // PV: O(16x128) += P(16x64) @ V_chunk(64x128).
#pragma unroll
        for (int kt2 = 0; kt2 < 2; ++kt2) {
            short8 a = *(const short8*)&Ps[wave * 16 + frow][kt2 * 32 + fko];
#pragma unroll
            for (int n = 0; n < 8; ++n) {
                short8 bf = *(const short8*)&VsT[n * 16 + frow][kt2 * 32 + fko];
                o_acc[n] = __builtin_amdgcn_mfma_f32_16x16x32_bf16(a, bf, o_acc[n], 0, 0, 0);
            }
        }
    }

    // Epilogue: O /= l, store bf16 [B,T,C]
#pragma unroll
    for (int r = 0; r < 4; ++r) {
        float rl = 1.f / fmaxf(l_i[r], 1e-30f);
        int t = t0 + wave * 16 + quad * 4 + r;
#pragma unroll
        for (int n = 0; n < 8; ++n) {
            float v = o_acc[n][r] * rl;
            O[((size_t)(b * T_ + t)) * C_ + h * D_ + n * 16 + frow] = f2bf(v);
        }
    }
}

// ---------------------------------------------------------------------------
extern "C" void kernel_launch(void* const* d_in, const int* in_sizes, int n_in,
                              void* d_out, int out_size, void* d_ws, size_t ws_size,
                              hipStream_t stream) {
    const float* x      = (const float*)d_in[0];
    const float* past_k = (const float*)d_in[1];
    const float* past_v = (const float*)d_in[2];
    const float* Wk     = (const float*)d_in[3];
    const float* Wq     = (const float*)d_in[4];
    const float* Wv     = (const float*)d_in[5];
    const float* Wp     = (const float*)d_in[6];
    const float* bp     = (const float*)d_in[7];

    float* out  = (float*)d_out;             // [B,T,C]    4,194,304 f32 (16 MB)
    float* kout = out + 4194304;             // [B,H,L,D]  8,388,608 f32
    float* vout = kout + 8388608;            // [B,H,L,D]  8,388,608 f32

    // Scratch: Q (bf16, 8 MB) lives in d_out's out region (dead until the final
    // GEMM overwrites it, after attn completes). O (bf16, 8 MB) in ws.
    u16* Qst = (u16*)d_out;
    u16* Ost = (u16*)d_ws;

    zero_ws_kernel<<<2048, 256, 0, stream>>>((u16x8*)Ost);

    copy_past_kernel<<<4096, 256, 0, stream>>>(
        (const float4*)past_k, (const float4*)past_v,
        (float4*)kout, (float4*)vout);

    dim3 g(32, 32);
    gemm_nt<1, 0><<<g, 256, 0, stream>>>(x, Wk, kout, nullptr);
    gemm_nt<1, 0><<<g, 256, 0, stream>>>(x, Wv, vout, nullptr);
    gemm_nt<0, 0><<<g, 256, 0, stream>>>(x, Wq, Qst, nullptr);

    attn_kernel<<<512, 256, 0, stream>>>(Qst, kout, vout, Ost);

    gemm_nt<2, 1><<<g, 256, 0, stream>>>(Ost, Wp, out, bp);
}